// Round 2
// baseline (444.756 us; speedup 1.0000x reference)
//
#include <hip/hip_runtime.h>
#include <stdint.h>

#define FDIM 8192
#define KSEL 512
#define NT   512
#define EPT  (FDIM / NT / 4)   // 4 uint4 (16 scalars) per thread per row
#define NBIN 4096
#define NWAVE (NT / 64)
#define NBLK 1024              // each block owns RPB rows, software-pipelined
#define RPB  (FDIM / NBLK)     // 8 rows per block

// Order-preserving float -> uint key (larger key <=> larger float), branchless
__device__ __forceinline__ unsigned keyOf(unsigned u) {
    return u ^ ((unsigned)((int)u >> 31) | 0x80000000u);
}
__device__ __forceinline__ float valOf(unsigned key) {
    unsigned u = (key & 0x80000000u) ? (key ^ 0x80000000u) : ~key;
    return __uint_as_float(u);
}

// Barrier draining ONLY the DS queue (lgkmcnt), NOT vmcnt.
// __syncthreads() emits s_waitcnt vmcnt(0) before s_barrier, which would
// drain the next-row prefetch loads we deliberately keep in flight across
// the radix rounds. LDS visibility needs only lgkmcnt(0)+s_barrier.
__device__ __forceinline__ void barrier_lgkm() {
    asm volatile("s_waitcnt lgkmcnt(0)" ::: "memory");
    __builtin_amdgcn_s_barrier();
}
// Full drain (rare tie path only): the float4 stores must be committed
// before t0's scalar overwrites of threshold-equal slots.
__device__ __forceinline__ void barrier_full() {
    asm volatile("s_waitcnt vmcnt(0) lgkmcnt(0)" ::: "memory");
    __builtin_amdgcn_s_barrier();
}

struct Shared {
    uint4 hist4[NBIN / 4];                 // 16 KiB histogram
    unsigned wtot[NWAVE];
    unsigned s_prefix, s_need;             // working state during rounds
    unsigned s_thresh, s_keepEq, s_eqCnt;  // final results (written round 2 only,
                                           // so next row's reset can't race readers)
    unsigned s_tiecnt;
    unsigned tiebuf[64];
};

__device__ __forceinline__ void process_row(
    const int row, const bool doPrefetch, const int nextRow,
    const float* __restrict__ x, float* __restrict__ out,
    uint4 (&cur)[EPT], uint4 (&nxt)[EPT],
    Shared& sh, const int t, const int lane, const int wave)
{
    // ---- Issue next row's loads FIRST; they stay in flight across all the
    //      radix-round barriers below (barrier_lgkm never drains vmcnt).
    if (doPrefetch) {
        const uint4* xr = (const uint4*)(x + (size_t)nextRow * FDIM);
        #pragma unroll
        for (int j = 0; j < EPT; ++j) nxt[j] = xr[j * NT + t];
    }

    // ---- Convert current row (loads issued one full row ago) to keys in place
    #pragma unroll
    for (int j = 0; j < EPT; ++j) {
        cur[j].x = keyOf(cur[j].x);
        cur[j].y = keyOf(cur[j].y);
        cur[j].z = keyOf(cur[j].z);
        cur[j].w = keyOf(cur[j].w);
    }
    if (t == 0) { sh.s_prefix = 0u; sh.s_need = KSEL; sh.s_tiecnt = 0u; }
    barrier_lgkm();

    unsigned* hist = (unsigned*)sh.hist4;

    // ---- Radix select, 3 rounds of 12/12/8 bits ----
    #pragma unroll
    for (int round = 0; round < 3; ++round) {
        const unsigned pref = sh.s_prefix;   // block-uniform
        const unsigned need = sh.s_need;

        if (round == 0) {
            #pragma unroll
            for (int j = 0; j < EPT; ++j) {
                #pragma unroll
                for (int c = 0; c < 4; ++c) {
                    unsigned key = (&cur[j].x)[c];
                    atomicAdd(&hist[key >> 20], 1u);
                }
            }
        } else if (round == 1) {
            #pragma unroll
            for (int j = 0; j < EPT; ++j) {
                #pragma unroll
                for (int c = 0; c < 4; ++c) {
                    unsigned key = (&cur[j].x)[c];
                    if ((key >> 20) == pref)                 // ~290 of 8192 match
                        atomicAdd(&hist[(key >> 8) & 0xFFFu], 1u);
                }
            }
        } else {
            #pragma unroll
            for (int j = 0; j < EPT; ++j) {
                #pragma unroll
                for (int c = 0; c < 4; ++c) {
                    unsigned key = (&cur[j].x)[c];
                    if ((key >> 8) == pref)                  // ~1-3 match
                        atomicAdd(&hist[key & 0xFFu], 1u);
                }
            }
        }
        barrier_lgkm();

        // ---- Hierarchical suffix-scan of 4096 bins: 8 bins/thread via two
        //      ds_read_b128 -> wave shfl scan -> 8 wave partials. Zero own
        //      bins with two ds_write_b128 for the next round.
        const unsigned b4 = (unsigned)t * 2u;
        const uint4 h0 = sh.hist4[b4];
        const uint4 h1 = sh.hist4[b4 + 1];
        unsigned sfx[9];                   // sfx[i] = sum of own bins [i..7]
        sfx[8] = 0u;
        sfx[7] = h1.w;
        sfx[6] = sfx[7] + h1.z;
        sfx[5] = sfx[6] + h1.y;
        sfx[4] = sfx[5] + h1.x;
        sfx[3] = sfx[4] + h0.w;
        sfx[2] = sfx[3] + h0.z;
        sfx[1] = sfx[2] + h0.y;
        sfx[0] = sfx[1] + h0.x;
        sh.hist4[b4]     = make_uint4(0u, 0u, 0u, 0u);
        sh.hist4[b4 + 1] = make_uint4(0u, 0u, 0u, 0u);
        const unsigned tot = sfx[0];
        unsigned incl = tot;               // inclusive suffix over lanes >= this
        #pragma unroll
        for (int off = 1; off < 64; off <<= 1) {
            unsigned y = __shfl_down(incl, off);
            incl += (lane + off < 64) ? y : 0u;
        }
        if (lane == 0) sh.wtot[wave] = incl;
        barrier_lgkm();

        unsigned gb = incl - tot;          // beyond-this-thread within wave
        #pragma unroll
        for (int w = 0; w < NWAVE; ++w) gb += (w > wave) ? sh.wtot[w] : 0u;

        // exactly one (thread, i) satisfies the straddle condition
        const unsigned base = (unsigned)t * (NBIN / NT);
        #pragma unroll
        for (int i = 0; i < 8; ++i) {
            unsigned S = gb + sfx[i];                  // count with digit >= base+i
            unsigned h = sfx[i] - sfx[i + 1];
            if (S >= need && S - h < need) {
                if (round == 2) {
                    sh.s_thresh = (pref << 8) | (base + (unsigned)i);
                    sh.s_keepEq = need - (S - h);
                    sh.s_eqCnt  = h;
                } else {
                    sh.s_prefix = (pref << 12) | (base + (unsigned)i);
                    sh.s_need   = need - (S - h);
                }
            }
        }
        barrier_lgkm();
    }

    const unsigned thresh = sh.s_thresh;   // exact key of the KSEL-th largest
    const unsigned keepEq = sh.s_keepEq;   // # threshold-equal elements to keep
    const unsigned eqCnt  = sh.s_eqCnt;    // total threshold-equal elements
    const bool simple = (eqCnt == keepEq);

    float4* orow = (float4*)(out + (size_t)row * FDIM);

    // ---- Output pass straight from registers (coalesced float4 stores) ----
    if (simple) {
        #pragma unroll
        for (int j = 0; j < EPT; ++j) {
            uint4 k = cur[j];
            float4 o;
            o.x = (k.x >= thresh) ? valOf(k.x) : 0.0f;
            o.y = (k.y >= thresh) ? valOf(k.y) : 0.0f;
            o.z = (k.z >= thresh) ? valOf(k.z) : 0.0f;
            o.w = (k.w >= thresh) ? valOf(k.w) : 0.0f;
            orow[j * NT + t] = o;
        }
    } else {
        #pragma unroll
        for (int j = 0; j < EPT; ++j) {
            uint4 k = cur[j];
            float4 o;
            o.x = (k.x > thresh) ? valOf(k.x) : 0.0f;
            o.y = (k.y > thresh) ? valOf(k.y) : 0.0f;
            o.z = (k.z > thresh) ? valOf(k.z) : 0.0f;
            o.w = (k.w > thresh) ? valOf(k.w) : 0.0f;
            orow[j * NT + t] = o;
        }
        // ---- Rare tie path: stable (lowest-index) selection among equals ----
        #pragma unroll
        for (int j = 0; j < EPT; ++j) {
            #pragma unroll
            for (int c = 0; c < 4; ++c) {
                unsigned key = (&cur[j].x)[c];
                if (key == thresh) {
                    unsigned slot = atomicAdd(&sh.s_tiecnt, 1u);
                    if (slot < 64u) sh.tiebuf[slot] = 4u * (unsigned)(j * NT + t) + (unsigned)c;
                }
            }
        }
        barrier_full();   // stores of this row must land before t0's overwrites
        if (t == 0) {
            const unsigned m = sh.s_tiecnt;
            const float v = valOf(thresh);
            if (m <= 64u) {
                for (unsigned i = 0; i < m; ++i) {
                    unsigned idx = sh.tiebuf[i], rank = 0;
                    for (unsigned q = 0; q < m; ++q) rank += (sh.tiebuf[q] < idx);
                    if (rank < keepEq) out[(size_t)row * FDIM + idx] = v;
                }
            } else {
                unsigned c = 0;
                for (int i = 0; i < FDIM && c < keepEq; ++i) {
                    if (keyOf(__float_as_uint(x[(size_t)row * FDIM + i])) == thresh) {
                        out[(size_t)row * FDIM + i] = v; ++c;
                    }
                }
            }
        }
    }
}

__global__ __launch_bounds__(NT, 4) void topk_mask_kernel(const float* __restrict__ x,
                                                          float* __restrict__ out) {
    __shared__ Shared sh;

    const int blk  = blockIdx.x;
    const int t    = threadIdx.x;
    const int lane = t & 63;
    const int wave = t >> 6;

    // Prologue: issue row(blk) loads, then zero the histogram under them.
    uint4 rawA[EPT], rawB[EPT];
    {
        const uint4* xr = (const uint4*)(x + (size_t)blk * FDIM);
        #pragma unroll
        for (int j = 0; j < EPT; ++j) rawA[j] = xr[j * NT + t];
    }
    #pragma unroll
    for (int i = t; i < NBIN / 4; i += NT) sh.hist4[i] = make_uint4(0u, 0u, 0u, 0u);
    // (visibility of the zeroing is covered by process_row's first barrier)

    // Concurrently-active rows are contiguous (row = r*NBLK + blk): all blocks
    // at pipeline step r stream a contiguous 32 MB slab — good HBM locality.
    #pragma unroll 1
    for (int r = 0; r < RPB; r += 2) {
        process_row(r * NBLK + blk, true, (r + 1) * NBLK + blk,
                    x, out, rawA, rawB, sh, t, lane, wave);
        process_row((r + 1) * NBLK + blk, (r + 2) < RPB, (r + 2) * NBLK + blk,
                    x, out, rawB, rawA, sh, t, lane, wave);
    }
}

extern "C" void kernel_launch(void* const* d_in, const int* in_sizes, int n_in,
                              void* d_out, int out_size, void* d_ws, size_t ws_size,
                              hipStream_t stream) {
    const float* x = (const float*)d_in[0];
    float* out = (float*)d_out;
    topk_mask_kernel<<<dim3(NBLK), dim3(NT), 0, stream>>>(x, out);
}

// Round 3
// 435.665 us; speedup vs baseline: 1.0209x; 1.0209x over previous
//
#include <hip/hip_runtime.h>
#include <stdint.h>

#define FDIM 8192
#define KSEL 512
#define NT   512
#define EPT  (FDIM / NT / 4)   // 4 uint4 (16 scalars) per thread
#define NBIN 4096              // round-0 bins (12-bit digit)
#define NBIN2 1024             // round-1/2 bins (10-bit digits)
#define NWAVE (NT / 64)

// Order-preserving float -> uint key (larger key <=> larger float)
__device__ __forceinline__ unsigned keyOf(unsigned u) {
    return (u & 0x80000000u) ? ~u : (u | 0x80000000u);
}
__device__ __forceinline__ float valOf(unsigned key) {
    unsigned u = (key & 0x80000000u) ? (key ^ 0x80000000u) : ~key;
    return __uint_as_float(u);
}

__global__ __launch_bounds__(NT) void topk_mask_kernel(const float* __restrict__ x,
                                                       float* __restrict__ out) {
    // 12/10/10 digit split: rounds 1-2 scan+zero only 1024 bins (4 KB) instead
    // of 4096 (16 KB). DS traffic/row drops ~162 KB -> ~114 KB; with ~4 blocks
    // resident/CU the DS pipe was the over-committed resource (HBM window per
    // row ~6400 cyc vs ~5100+ cyc DS), so this moves DS off the critical path.
    __shared__ uint4 hist4[NBIN / 4];      // 16 KiB histogram
    unsigned* hist = (unsigned*)hist4;
    uint2*    hist2 = (uint2*)hist4;
    __shared__ unsigned wtot[NWAVE];
    __shared__ unsigned s_prefix, s_need, s_sub, s_tiecnt;
    __shared__ unsigned tiebuf[64];

    const int row  = blockIdx.x;
    const int t    = threadIdx.x;
    const int lane = t & 63;
    const int wave = t >> 6;

    const float4* xrow = (const float4*)(x + (size_t)row * FDIM);
    float4*       orow = (float4*)(out + (size_t)row * FDIM);

    // ---- Load row into registers as order-preserving keys (coalesced float4) ----
    uint4 kreg[EPT];
    #pragma unroll
    for (int j = 0; j < EPT; ++j) {
        float4 v = xrow[j * NT + t];
        kreg[j].x = keyOf(__float_as_uint(v.x));
        kreg[j].y = keyOf(__float_as_uint(v.y));
        kreg[j].z = keyOf(__float_as_uint(v.z));
        kreg[j].w = keyOf(__float_as_uint(v.w));
    }
    #pragma unroll
    for (int i = t; i < NBIN / 4; i += NT) hist4[i] = make_uint4(0u, 0u, 0u, 0u);
    if (t == 0) { s_prefix = 0u; s_need = KSEL; s_tiecnt = 0u; }
    __syncthreads();

    // ---- Radix select, 3 rounds of 12/10/10 bits ----
    #pragma unroll
    for (int round = 0; round < 3; ++round) {
        const unsigned pref = s_prefix;   // block-uniform, stable until end-of-round
        const unsigned need = s_need;

        if (round == 0) {
            #pragma unroll
            for (int j = 0; j < EPT; ++j) {
                #pragma unroll
                for (int c = 0; c < 4; ++c) {
                    unsigned key = (&kreg[j].x)[c];
                    atomicAdd(&hist[key >> 20], 1u);
                }
            }
        } else if (round == 1) {
            #pragma unroll
            for (int j = 0; j < EPT; ++j) {
                #pragma unroll
                for (int c = 0; c < 4; ++c) {
                    unsigned key = (&kreg[j].x)[c];
                    if ((key >> 20) == pref)                       // ~290 of 8192 match
                        atomicAdd(&hist[(key >> 10) & 0x3FFu], 1u);
                }
            }
        } else {
            #pragma unroll
            for (int j = 0; j < EPT; ++j) {
                #pragma unroll
                for (int c = 0; c < 4; ++c) {
                    unsigned key = (&kreg[j].x)[c];
                    if ((key >> 10) == pref)                       // few match
                        atomicAdd(&hist[key & 0x3FFu], 1u);
                }
            }
        }
        __syncthreads();

        if (round == 0) {
            // ---- 4096-bin suffix-scan: 8 bins/thread via two ds_read_b128 ->
            //      wave shfl scan -> 8 wave partials. Zero own bins (b128).
            const unsigned b4 = (unsigned)t * 2u;
            const uint4 h0 = hist4[b4];
            const uint4 h1 = hist4[b4 + 1];
            unsigned sfx[9];                   // sfx[i] = sum of own bins [i..7]
            sfx[8] = 0u;
            sfx[7] = h1.w;
            sfx[6] = sfx[7] + h1.z;
            sfx[5] = sfx[6] + h1.y;
            sfx[4] = sfx[5] + h1.x;
            sfx[3] = sfx[4] + h0.w;
            sfx[2] = sfx[3] + h0.z;
            sfx[1] = sfx[2] + h0.y;
            sfx[0] = sfx[1] + h0.x;
            hist4[b4]     = make_uint4(0u, 0u, 0u, 0u);   // ready for round 1
            hist4[b4 + 1] = make_uint4(0u, 0u, 0u, 0u);
            const unsigned tot = sfx[0];
            unsigned incl = tot;               // inclusive suffix over lanes >= this
            #pragma unroll
            for (int off = 1; off < 64; off <<= 1) {
                unsigned y = __shfl_down(incl, off);
                incl += (lane + off < 64) ? y : 0u;
            }
            if (lane == 0) wtot[wave] = incl;
            __syncthreads();
            unsigned gb = incl - tot;          // beyond-this-thread within wave
            #pragma unroll
            for (int w = 0; w < NWAVE; ++w) gb += (w > wave) ? wtot[w] : 0u;

            const unsigned base = (unsigned)t * 8u;
            #pragma unroll
            for (int i = 0; i < 8; ++i) {
                unsigned S = gb + sfx[i];                  // count with digit >= base+i
                unsigned h = sfx[i] - sfx[i + 1];
                if (S >= need && S - h < need) {
                    s_prefix = base + (unsigned)i;         // 12-bit prefix
                    s_need = need - (S - h);
                    s_sub  = h;
                }
            }
        } else {
            // ---- 1024-bin suffix-scan: 2 bins/thread via one ds_read_b64.
            const uint2 h = hist2[t];
            unsigned sfx[3];
            sfx[2] = 0u;
            sfx[1] = h.y;
            sfx[0] = h.y + h.x;
            hist2[t] = make_uint2(0u, 0u);     // ready for next round
            const unsigned tot = sfx[0];
            unsigned incl = tot;
            #pragma unroll
            for (int off = 1; off < 64; off <<= 1) {
                unsigned y = __shfl_down(incl, off);
                incl += (lane + off < 64) ? y : 0u;
            }
            if (lane == 0) wtot[wave] = incl;
            __syncthreads();
            unsigned gb = incl - tot;
            #pragma unroll
            for (int w = 0; w < NWAVE; ++w) gb += (w > wave) ? wtot[w] : 0u;

            const unsigned base = (unsigned)t * 2u;
            #pragma unroll
            for (int i = 0; i < 2; ++i) {
                unsigned S = gb + sfx[i];
                unsigned h2 = sfx[i] - sfx[i + 1];
                if (S >= need && S - h2 < need) {
                    s_prefix = (pref << 10) | (base + (unsigned)i);  // 22b / 32b
                    s_need = need - (S - h2);
                    s_sub  = h2;
                }
            }
        }
        __syncthreads();
    }

    const unsigned thresh = s_prefix;   // exact key of the KSEL-th largest
    const unsigned keepEq = s_need;     // # threshold-equal elements to keep
    const unsigned eqCnt  = s_sub;      // total threshold-equal elements
    const bool simple = (eqCnt == keepEq);

    // ---- Output pass straight from registers (coalesced float4 stores) ----
    if (simple) {
        #pragma unroll
        for (int j = 0; j < EPT; ++j) {
            uint4 k = kreg[j];
            float4 o;
            o.x = (k.x >= thresh) ? valOf(k.x) : 0.0f;
            o.y = (k.y >= thresh) ? valOf(k.y) : 0.0f;
            o.z = (k.z >= thresh) ? valOf(k.z) : 0.0f;
            o.w = (k.w >= thresh) ? valOf(k.w) : 0.0f;
            orow[j * NT + t] = o;
        }
    } else {
        #pragma unroll
        for (int j = 0; j < EPT; ++j) {
            uint4 k = kreg[j];
            float4 o;
            o.x = (k.x > thresh) ? valOf(k.x) : 0.0f;
            o.y = (k.y > thresh) ? valOf(k.y) : 0.0f;
            o.z = (k.z > thresh) ? valOf(k.z) : 0.0f;
            o.w = (k.w > thresh) ? valOf(k.w) : 0.0f;
            orow[j * NT + t] = o;
        }
        // ---- Rare tie path: stable (lowest-index) selection among equals ----
        #pragma unroll
        for (int j = 0; j < EPT; ++j) {
            #pragma unroll
            for (int c = 0; c < 4; ++c) {
                unsigned key = (&kreg[j].x)[c];
                if (key == thresh) {
                    unsigned slot = atomicAdd(&s_tiecnt, 1u);
                    if (slot < 64u) tiebuf[slot] = 4u * (unsigned)(j * NT + t) + (unsigned)c;
                }
            }
        }
        __syncthreads();
        if (t == 0) {
            const unsigned m = s_tiecnt;
            const float v = valOf(thresh);
            if (m <= 64u) {
                for (unsigned i = 0; i < m; ++i) {
                    unsigned idx = tiebuf[i], rank = 0;
                    for (unsigned q = 0; q < m; ++q) rank += (tiebuf[q] < idx);
                    if (rank < keepEq) out[(size_t)row * FDIM + idx] = v;
                }
            } else {
                unsigned c = 0;
                for (int i = 0; i < FDIM && c < keepEq; ++i) {
                    if (keyOf(__float_as_uint(x[(size_t)row * FDIM + i])) == thresh) {
                        out[(size_t)row * FDIM + i] = v; ++c;
                    }
                }
            }
        }
    }
}

extern "C" void kernel_launch(void* const* d_in, const int* in_sizes, int n_in,
                              void* d_out, int out_size, void* d_ws, size_t ws_size,
                              hipStream_t stream) {
    const float* x = (const float*)d_in[0];
    float* out = (float*)d_out;
    topk_mask_kernel<<<dim3(FDIM), dim3(NT), 0, stream>>>(x, out);
}

// Round 4
// 433.205 us; speedup vs baseline: 1.0267x; 1.0057x over previous
//
#include <hip/hip_runtime.h>
#include <stdint.h>

#define FDIM 8192
#define KSEL 512
#define NT   512
#define EPT  (FDIM / NT / 4)   // 4 uint4 (16 scalars) per thread
#define NBINP 2048             // round-0 bins per sign phase (11-bit digit)
#define NWAVE (NT / 64)

// Order-preserving float -> uint key (larger key <=> larger float)
__device__ __forceinline__ unsigned keyOf(unsigned u) {
    return (u & 0x80000000u) ? ~u : (u | 0x80000000u);
}
__device__ __forceinline__ float valOf(unsigned key) {
    unsigned u = (key & 0x80000000u) ? (key ^ 0x80000000u) : ~key;
    return __uint_as_float(u);
}

__global__ __launch_bounds__(NT) void topk_mask_kernel(const float* __restrict__ x,
                                                       float* __restrict__ out) {
    // Round 0 counts ONLY positive-side keys (top bit set) into 2048 bins:
    // K=512 of 8192 sits in the top 6.25%, which for this data is entirely
    // positive. Halving active lanes per DS-atomic instruction roughly halves
    // the hot-bin serialization that made the DS pipe critical (~6400 cyc/row
    // of atomics vs a 6400-cyc HBM window). Exact fallback to negatives if
    // the positive count < need (block-uniform, never taken on this data).
    __shared__ uint4 hist4[NBINP / 4];     // 8 KiB histogram
    unsigned* hist  = (unsigned*)hist4;
    uint2*    hist2 = (uint2*)hist4;
    __shared__ unsigned wtot[NWAVE];
    __shared__ unsigned s_prefix, s_need, s_sub, s_tiecnt;
    __shared__ unsigned tiebuf[64];

    const int row  = blockIdx.x;
    const int t    = threadIdx.x;
    const int lane = t & 63;
    const int wave = t >> 6;

    const float4* xrow = (const float4*)(x + (size_t)row * FDIM);
    float4*       orow = (float4*)(out + (size_t)row * FDIM);

    // ---- Load row into registers as order-preserving keys (coalesced float4) ----
    uint4 kreg[EPT];
    #pragma unroll
    for (int j = 0; j < EPT; ++j) {
        float4 v = xrow[j * NT + t];
        kreg[j].x = keyOf(__float_as_uint(v.x));
        kreg[j].y = keyOf(__float_as_uint(v.y));
        kreg[j].z = keyOf(__float_as_uint(v.z));
        kreg[j].w = keyOf(__float_as_uint(v.w));
    }
    hist4[t] = make_uint4(0u, 0u, 0u, 0u);   // NBINP/4 == NT: one uint4 each
    if (t == 0) s_tiecnt = 0u;
    __syncthreads();

    // 2048-bin suffix-scan + straddle search; zeroes the bins it reads.
    // Returns the grand total of counted keys (block-uniform).
    auto scan2048 = [&](unsigned needP, unsigned prefOr) -> unsigned {
        const uint4 h0 = hist4[t];
        unsigned sfx[5];                    // sfx[i] = sum of own bins [i..3]
        sfx[4] = 0u;
        sfx[3] = h0.w;
        sfx[2] = sfx[3] + h0.z;
        sfx[1] = sfx[2] + h0.y;
        sfx[0] = sfx[1] + h0.x;
        hist4[t] = make_uint4(0u, 0u, 0u, 0u);   // ready for next phase/round
        const unsigned tot = sfx[0];
        unsigned incl = tot;                // inclusive suffix over lanes >= this
        #pragma unroll
        for (int off = 1; off < 64; off <<= 1) {
            unsigned y = __shfl_down(incl, off);
            incl += (lane + off < 64) ? y : 0u;
        }
        if (lane == 0) wtot[wave] = incl;
        __syncthreads();
        unsigned gb = incl - tot, grand = 0u;
        #pragma unroll
        for (int w = 0; w < NWAVE; ++w) {
            grand += wtot[w];
            gb += (w > wave) ? wtot[w] : 0u;
        }
        const unsigned base = (unsigned)t * 4u;
        #pragma unroll
        for (int i = 0; i < 4; ++i) {
            unsigned S = gb + sfx[i];                  // count with digit >= base+i
            unsigned h = sfx[i] - sfx[i + 1];
            if (S >= needP && S - h < needP) {         // at most one (t,i) hits
                s_prefix = prefOr | (base + (unsigned)i);   // 12-bit prefix
                s_need   = needP - (S - h);
                s_sub    = h;
            }
        }
        return grand;
    };

    // ---- Round 0: sign-partitioned 11-bit digit ----
    {
        unsigned need = KSEL;
        #pragma unroll
        for (int j = 0; j < EPT; ++j) {
            #pragma unroll
            for (int c = 0; c < 4; ++c) {
                unsigned key = (&kreg[j].x)[c];
                if (key & 0x80000000u)                 // positive side only
                    atomicAdd(&hist[(key >> 20) & 0x7FFu], 1u);
            }
        }
        __syncthreads();
        unsigned grand = scan2048(need, 0x800u);
        __syncthreads();
        if (grand < need) {                            // exact fallback (rare)
            need -= grand;                             // all positives are kept
            #pragma unroll
            for (int j = 0; j < EPT; ++j) {
                #pragma unroll
                for (int c = 0; c < 4; ++c) {
                    unsigned key = (&kreg[j].x)[c];
                    if (!(key & 0x80000000u))          // negative side
                        atomicAdd(&hist[key >> 20], 1u);
                }
            }
            __syncthreads();
            (void)scan2048(need, 0u);
            __syncthreads();
        }
    }

    // ---- Rounds 1-2: 10-bit digits over 1024 bins ----
    #pragma unroll
    for (int round = 1; round < 3; ++round) {
        const unsigned pref = s_prefix;   // block-uniform, stable until end-of-round
        const unsigned need = s_need;

        if (round == 1) {
            #pragma unroll
            for (int j = 0; j < EPT; ++j) {
                #pragma unroll
                for (int c = 0; c < 4; ++c) {
                    unsigned key = (&kreg[j].x)[c];
                    if ((key >> 20) == pref)                       // ~290 of 8192 match
                        atomicAdd(&hist[(key >> 10) & 0x3FFu], 1u);
                }
            }
        } else {
            #pragma unroll
            for (int j = 0; j < EPT; ++j) {
                #pragma unroll
                for (int c = 0; c < 4; ++c) {
                    unsigned key = (&kreg[j].x)[c];
                    if ((key >> 10) == pref)                       // few match
                        atomicAdd(&hist[key & 0x3FFu], 1u);
                }
            }
        }
        __syncthreads();

        // 1024-bin suffix-scan: 2 bins/thread via one ds_read_b64.
        const uint2 h = hist2[t];
        unsigned sfx[3];
        sfx[2] = 0u;
        sfx[1] = h.y;
        sfx[0] = h.y + h.x;
        hist2[t] = make_uint2(0u, 0u);     // ready for next round
        const unsigned tot = sfx[0];
        unsigned incl = tot;
        #pragma unroll
        for (int off = 1; off < 64; off <<= 1) {
            unsigned y = __shfl_down(incl, off);
            incl += (lane + off < 64) ? y : 0u;
        }
        if (lane == 0) wtot[wave] = incl;
        __syncthreads();
        unsigned gb = incl - tot;
        #pragma unroll
        for (int w = 0; w < NWAVE; ++w) gb += (w > wave) ? wtot[w] : 0u;

        const unsigned base = (unsigned)t * 2u;
        #pragma unroll
        for (int i = 0; i < 2; ++i) {
            unsigned S = gb + sfx[i];
            unsigned h2 = sfx[i] - sfx[i + 1];
            if (S >= need && S - h2 < need) {
                s_prefix = (pref << 10) | (base + (unsigned)i);  // 22b / 32b
                s_need = need - (S - h2);
                s_sub  = h2;
            }
        }
        __syncthreads();
    }

    const unsigned thresh = s_prefix;   // exact key of the KSEL-th largest
    const unsigned keepEq = s_need;     // # threshold-equal elements to keep
    const unsigned eqCnt  = s_sub;      // total threshold-equal elements
    const bool simple = (eqCnt == keepEq);

    // ---- Output pass straight from registers (coalesced float4 stores) ----
    if (simple) {
        #pragma unroll
        for (int j = 0; j < EPT; ++j) {
            uint4 k = kreg[j];
            float4 o;
            o.x = (k.x >= thresh) ? valOf(k.x) : 0.0f;
            o.y = (k.y >= thresh) ? valOf(k.y) : 0.0f;
            o.z = (k.z >= thresh) ? valOf(k.z) : 0.0f;
            o.w = (k.w >= thresh) ? valOf(k.w) : 0.0f;
            orow[j * NT + t] = o;
        }
    } else {
        #pragma unroll
        for (int j = 0; j < EPT; ++j) {
            uint4 k = kreg[j];
            float4 o;
            o.x = (k.x > thresh) ? valOf(k.x) : 0.0f;
            o.y = (k.y > thresh) ? valOf(k.y) : 0.0f;
            o.z = (k.z > thresh) ? valOf(k.z) : 0.0f;
            o.w = (k.w > thresh) ? valOf(k.w) : 0.0f;
            orow[j * NT + t] = o;
        }
        // ---- Rare tie path: stable (lowest-index) selection among equals ----
        #pragma unroll
        for (int j = 0; j < EPT; ++j) {
            #pragma unroll
            for (int c = 0; c < 4; ++c) {
                unsigned key = (&kreg[j].x)[c];
                if (key == thresh) {
                    unsigned slot = atomicAdd(&s_tiecnt, 1u);
                    if (slot < 64u) tiebuf[slot] = 4u * (unsigned)(j * NT + t) + (unsigned)c;
                }
            }
        }
        __syncthreads();
        if (t == 0) {
            const unsigned m = s_tiecnt;
            const float v = valOf(thresh);
            if (m <= 64u) {
                for (unsigned i = 0; i < m; ++i) {
                    unsigned idx = tiebuf[i], rank = 0;
                    for (unsigned q = 0; q < m; ++q) rank += (tiebuf[q] < idx);
                    if (rank < keepEq) out[(size_t)row * FDIM + idx] = v;
                }
            } else {
                unsigned c = 0;
                for (int i = 0; i < FDIM && c < keepEq; ++i) {
                    if (keyOf(__float_as_uint(x[(size_t)row * FDIM + i])) == thresh) {
                        out[(size_t)row * FDIM + i] = v; ++c;
                    }
                }
            }
        }
    }
}

extern "C" void kernel_launch(void* const* d_in, const int* in_sizes, int n_in,
                              void* d_out, int out_size, void* d_ws, size_t ws_size,
                              hipStream_t stream) {
    const float* x = (const float*)d_in[0];
    float* out = (float*)d_out;
    topk_mask_kernel<<<dim3(FDIM), dim3(NT), 0, stream>>>(x, out);
}

// Round 5
// 431.026 us; speedup vs baseline: 1.0319x; 1.0051x over previous
//
#include <hip/hip_runtime.h>
#include <stdint.h>

#define FDIM 8192
#define KSEL 512
#define NT   512
#define EPT  (FDIM / NT / 4)   // 4 uint4 (16 scalars) per thread
#define NBINP 2048             // round-0 bins (11-bit digit, positive side)
#define NWAVE (NT / 64)

// Order-preserving float -> uint key (larger key <=> larger float)
__device__ __forceinline__ unsigned keyOf(unsigned u) {
    return (u & 0x80000000u) ? ~u : (u | 0x80000000u);
}
__device__ __forceinline__ float valOf(unsigned key) {
    unsigned u = (key & 0x80000000u) ? (key ^ 0x80000000u) : ~key;
    return __uint_as_float(u);
}

// Barrier draining ONLY LDS/SMEM (lgkmcnt), NOT vmcnt: __syncthreads() emits
// s_waitcnt vmcnt(0) before s_barrier, which would serialize the whole row
// load ahead of any counting. Counting chunk j only needs load j (compiler
// emits partial vmcnt waits per use); LDS visibility needs only lgkmcnt(0).
__device__ __forceinline__ void barrier_lgkm() {
    asm volatile("s_waitcnt lgkmcnt(0)" ::: "memory");
    __builtin_amdgcn_s_barrier();
}
// Full drain (rare tie path only): float4 stores must be committed before
// t0's scalar overwrites of threshold-equal slots.
__device__ __forceinline__ void barrier_full() {
    asm volatile("s_waitcnt vmcnt(0) lgkmcnt(0)" ::: "memory");
    __builtin_amdgcn_s_barrier();
}

__global__ __launch_bounds__(NT) void topk_mask_kernel(const float* __restrict__ x,
                                                       float* __restrict__ out) {
    __shared__ uint4 hist4[NBINP / 4];     // 8 KiB histogram
    unsigned* hist  = (unsigned*)hist4;
    uint2*    hist2 = (uint2*)hist4;
    __shared__ unsigned wtot[NWAVE];
    __shared__ unsigned s_prefix, s_need, s_sub, s_tiecnt;
    __shared__ unsigned tiebuf[64];

    const int row  = blockIdx.x;
    const int t    = threadIdx.x;
    const int lane = t & 63;
    const int wave = t >> 6;

    const uint4* xrow = (const uint4*)(x + (size_t)row * FDIM);
    float4*      orow = (float4*)(out + (size_t)row * FDIM);

    // ---- Issue ALL row loads first; nothing below drains vmcnt until a
    //      chunk's data is actually consumed.
    uint4 kreg[EPT];
    #pragma unroll
    for (int j = 0; j < EPT; ++j) kreg[j] = xrow[j * NT + t];

    hist4[t] = make_uint4(0u, 0u, 0u, 0u);   // NBINP/4 == NT: one uint4 each
    if (t == 0) s_tiecnt = 0u;
    barrier_lgkm();

    // 2048-bin suffix-scan + straddle search; zeroes the bins it reads.
    // Returns the grand total of counted keys (block-uniform).
    auto scan2048 = [&](unsigned needP, unsigned prefOr) -> unsigned {
        const uint4 h0 = hist4[t];
        unsigned sfx[5];                    // sfx[i] = sum of own bins [i..3]
        sfx[4] = 0u;
        sfx[3] = h0.w;
        sfx[2] = sfx[3] + h0.z;
        sfx[1] = sfx[2] + h0.y;
        sfx[0] = sfx[1] + h0.x;
        hist4[t] = make_uint4(0u, 0u, 0u, 0u);   // ready for next phase/round
        const unsigned tot = sfx[0];
        unsigned incl = tot;                // inclusive suffix over lanes >= this
        #pragma unroll
        for (int off = 1; off < 64; off <<= 1) {
            unsigned y = __shfl_down(incl, off);
            incl += (lane + off < 64) ? y : 0u;
        }
        if (lane == 0) wtot[wave] = incl;
        barrier_lgkm();
        unsigned gb = incl - tot, grand = 0u;
        #pragma unroll
        for (int w = 0; w < NWAVE; ++w) {
            grand += wtot[w];
            gb += (w > wave) ? wtot[w] : 0u;
        }
        const unsigned base = (unsigned)t * 4u;
        #pragma unroll
        for (int i = 0; i < 4; ++i) {
            unsigned S = gb + sfx[i];                  // count with digit >= base+i
            unsigned h = sfx[i] - sfx[i + 1];
            if (S >= needP && S - h < needP) {         // at most one (t,i) hits
                s_prefix = prefOr | (base + (unsigned)i);   // 12-bit prefix
                s_need   = needP - (S - h);
                s_sub    = h;
            }
        }
        return grand;
    };

    // ---- Round 0: convert + count chunk-by-chunk as loads land.
    //      Chunk j's atomics depend only on load j -> partial vmcnt waits;
    //      counting overlaps the tail of the load stream.
    {
        unsigned need = KSEL;
        #pragma unroll
        for (int j = 0; j < EPT; ++j) {
            kreg[j].x = keyOf(kreg[j].x);
            kreg[j].y = keyOf(kreg[j].y);
            kreg[j].z = keyOf(kreg[j].z);
            kreg[j].w = keyOf(kreg[j].w);
            #pragma unroll
            for (int c = 0; c < 4; ++c) {
                unsigned key = (&kreg[j].x)[c];
                if (key & 0x80000000u)                 // positive side only
                    atomicAdd(&hist[(key >> 20) & 0x7FFu], 1u);
            }
        }
        barrier_lgkm();
        unsigned grand = scan2048(need, 0x800u);
        barrier_lgkm();
        if (grand < need) {                            // exact fallback (rare)
            need -= grand;                             // all positives are kept
            #pragma unroll
            for (int j = 0; j < EPT; ++j) {
                #pragma unroll
                for (int c = 0; c < 4; ++c) {
                    unsigned key = (&kreg[j].x)[c];
                    if (!(key & 0x80000000u))          // negative side
                        atomicAdd(&hist[key >> 20], 1u);
                }
            }
            barrier_lgkm();
            (void)scan2048(need, 0u);
            barrier_lgkm();
        }
    }

    // ---- Rounds 1-2: 10-bit digits over 1024 bins ----
    #pragma unroll
    for (int round = 1; round < 3; ++round) {
        const unsigned pref = s_prefix;   // block-uniform, stable until end-of-round
        const unsigned need = s_need;

        if (round == 1) {
            #pragma unroll
            for (int j = 0; j < EPT; ++j) {
                #pragma unroll
                for (int c = 0; c < 4; ++c) {
                    unsigned key = (&kreg[j].x)[c];
                    if ((key >> 20) == pref)                       // ~290 of 8192 match
                        atomicAdd(&hist[(key >> 10) & 0x3FFu], 1u);
                }
            }
        } else {
            #pragma unroll
            for (int j = 0; j < EPT; ++j) {
                #pragma unroll
                for (int c = 0; c < 4; ++c) {
                    unsigned key = (&kreg[j].x)[c];
                    if ((key >> 10) == pref)                       // few match
                        atomicAdd(&hist[key & 0x3FFu], 1u);
                }
            }
        }
        barrier_lgkm();

        // 1024-bin suffix-scan: 2 bins/thread via one ds_read_b64.
        const uint2 h = hist2[t];
        unsigned sfx[3];
        sfx[2] = 0u;
        sfx[1] = h.y;
        sfx[0] = h.y + h.x;
        hist2[t] = make_uint2(0u, 0u);     // ready for next round
        const unsigned tot = sfx[0];
        unsigned incl = tot;
        #pragma unroll
        for (int off = 1; off < 64; off <<= 1) {
            unsigned y = __shfl_down(incl, off);
            incl += (lane + off < 64) ? y : 0u;
        }
        if (lane == 0) wtot[wave] = incl;
        barrier_lgkm();
        unsigned gb = incl - tot;
        #pragma unroll
        for (int w = 0; w < NWAVE; ++w) gb += (w > wave) ? wtot[w] : 0u;

        const unsigned base = (unsigned)t * 2u;
        #pragma unroll
        for (int i = 0; i < 2; ++i) {
            unsigned S = gb + sfx[i];
            unsigned h2 = sfx[i] - sfx[i + 1];
            if (S >= need && S - h2 < need) {
                s_prefix = (pref << 10) | (base + (unsigned)i);  // 22b / 32b
                s_need = need - (S - h2);
                s_sub  = h2;
            }
        }
        barrier_lgkm();
    }

    const unsigned thresh = s_prefix;   // exact key of the KSEL-th largest
    const unsigned keepEq = s_need;     // # threshold-equal elements to keep
    const unsigned eqCnt  = s_sub;      // total threshold-equal elements
    const bool simple = (eqCnt == keepEq);

    // ---- Output pass straight from registers (coalesced float4 stores) ----
    if (simple) {
        #pragma unroll
        for (int j = 0; j < EPT; ++j) {
            uint4 k = kreg[j];
            float4 o;
            o.x = (k.x >= thresh) ? valOf(k.x) : 0.0f;
            o.y = (k.y >= thresh) ? valOf(k.y) : 0.0f;
            o.z = (k.z >= thresh) ? valOf(k.z) : 0.0f;
            o.w = (k.w >= thresh) ? valOf(k.w) : 0.0f;
            orow[j * NT + t] = o;
        }
    } else {
        #pragma unroll
        for (int j = 0; j < EPT; ++j) {
            uint4 k = kreg[j];
            float4 o;
            o.x = (k.x > thresh) ? valOf(k.x) : 0.0f;
            o.y = (k.y > thresh) ? valOf(k.y) : 0.0f;
            o.z = (k.z > thresh) ? valOf(k.z) : 0.0f;
            o.w = (k.w > thresh) ? valOf(k.w) : 0.0f;
            orow[j * NT + t] = o;
        }
        // ---- Rare tie path: stable (lowest-index) selection among equals ----
        #pragma unroll
        for (int j = 0; j < EPT; ++j) {
            #pragma unroll
            for (int c = 0; c < 4; ++c) {
                unsigned key = (&kreg[j].x)[c];
                if (key == thresh) {
                    unsigned slot = atomicAdd(&s_tiecnt, 1u);
                    if (slot < 64u) tiebuf[slot] = 4u * (unsigned)(j * NT + t) + (unsigned)c;
                }
            }
        }
        barrier_full();   // this row's stores must land before t0's overwrites
        if (t == 0) {
            const unsigned m = s_tiecnt;
            const float v = valOf(thresh);
            if (m <= 64u) {
                for (unsigned i = 0; i < m; ++i) {
                    unsigned idx = tiebuf[i], rank = 0;
                    for (unsigned q = 0; q < m; ++q) rank += (tiebuf[q] < idx);
                    if (rank < keepEq) out[(size_t)row * FDIM + idx] = v;
                }
            } else {
                unsigned c = 0;
                for (int i = 0; i < FDIM && c < keepEq; ++i) {
                    if (keyOf(__float_as_uint(x[(size_t)row * FDIM + i])) == thresh) {
                        out[(size_t)row * FDIM + i] = v; ++c;
                    }
                }
            }
        }
    }
}

extern "C" void kernel_launch(void* const* d_in, const int* in_sizes, int n_in,
                              void* d_out, int out_size, void* d_ws, size_t ws_size,
                              hipStream_t stream) {
    const float* x = (const float*)d_in[0];
    float* out = (float*)d_out;
    topk_mask_kernel<<<dim3(FDIM), dim3(NT), 0, stream>>>(x, out);
}